// Round 3
// baseline (932.008 us; speedup 1.0000x reference)
//
#include <hip/hip_runtime.h>

#define N_NODES    100000
#define N_EDGES    1600000
#define DIM        128
#define OUT_CH     10
#define NUM_GRAPHS 128
#define BN_EPS     1e-5f

// bucket partition params
#define BSHIFT   10
#define NB       98          // ceil(100000 / 1024)
#define CAP      24576       // expected 16384/bucket, +64 sigma
#define SLICES   3
#define SLICE_SLOTS 8192

typedef __attribute__((ext_vector_type(8))) short short8;
typedef __attribute__((ext_vector_type(4))) float floatx4;

__device__ inline float bf2f(unsigned short u) {
    union { unsigned i; float f; } v; v.i = (unsigned)u << 16; return v.f;
}
__device__ inline unsigned short f2bf(float f) {
    union { float f; unsigned i; } v; v.f = f;
    unsigned r = (v.i + 0x7fffu + ((v.i >> 16) & 1u)) >> 16;
    return (unsigned short)r;
}

// ===================== bucket partition (src,dst) by dst>>10 =====================
__global__ __launch_bounds__(256)
void k_bucket(const int* __restrict__ src, const int* __restrict__ dst,
              int* __restrict__ gcur, uint2* __restrict__ pairs) {
    __shared__ int h[NB];
    int t = threadIdx.x;
    if (t < NB) h[t] = 0;
    __syncthreads();
    int base = blockIdx.x * 4096;
    #pragma unroll
    for (int i = 0; i < 16; ++i) {
        int idx = base + i * 256 + t;
        if (idx < N_EDGES) atomicAdd(&h[dst[idx] >> BSHIFT], 1);
    }
    __syncthreads();
    if (t < NB) h[t] = atomicAdd(&gcur[t], h[t]);   // h[b] becomes this block's base
    __syncthreads();
    #pragma unroll
    for (int i = 0; i < 16; ++i) {
        int idx = base + i * 256 + t;
        if (idx < N_EDGES) {
            int d = dst[idx];
            int b = d >> BSHIFT;
            int pos = atomicAdd(&h[b], 1);
            if (pos < CAP) pairs[(size_t)b * CAP + pos] = make_uint2((unsigned)src[idx], (unsigned)d);
        }
    }
}

// per-bucket fine counts with LDS-local histogram
__global__ __launch_bounds__(256)
void k_count2(const uint2* __restrict__ pairs, const int* __restrict__ gcur,
              int* __restrict__ cnt) {
    __shared__ int lc[1024];
    int bi = blockIdx.x / SLICES, s = blockIdx.x % SLICES;
    int t = threadIdx.x;
    for (int i = t; i < 1024; i += 256) lc[i] = 0;
    __syncthreads();
    int n  = min(gcur[bi], CAP);
    int lo = s * SLICE_SLOTS, hi = min(lo + SLICE_SLOTS, n);
    const uint2* P = pairs + (size_t)bi * CAP;
    for (int i = lo + t; i < hi; i += 256)
        atomicAdd(&lc[P[i].y & 1023], 1);
    __syncthreads();
    int nb0 = bi << BSHIFT;
    for (int i = t; i < 1024; i += 256)
        if (lc[i] > 0) atomicAdd(&cnt[nb0 + i], lc[i]);
}

// per-bucket fill with block-claimed per-dst ranges (L2-local col writes)
__global__ __launch_bounds__(256)
void k_fill2(const uint2* __restrict__ pairs, const int* __restrict__ gcur,
             int* __restrict__ cursor, int* __restrict__ col) {
    __shared__ int lc[1024];
    __shared__ int lb[1024];
    int bi = blockIdx.x / SLICES, s = blockIdx.x % SLICES;
    int t = threadIdx.x;
    for (int i = t; i < 1024; i += 256) lc[i] = 0;
    __syncthreads();
    int n  = min(gcur[bi], CAP);
    int lo = s * SLICE_SLOTS, hi = min(lo + SLICE_SLOTS, n);
    const uint2* P = pairs + (size_t)bi * CAP;
    int nb0 = bi << BSHIFT;
    for (int i = lo + t; i < hi; i += 256)
        atomicAdd(&lc[P[i].y & 1023], 1);
    __syncthreads();
    for (int i = t; i < 1024; i += 256)
        lb[i] = (lc[i] > 0) ? atomicAdd(&cursor[nb0 + i], lc[i]) : 0;
    __syncthreads();
    for (int i = lo + t; i < hi; i += 256) {
        uint2 e = P[i];
        int p = atomicAdd(&lb[e.y & 1023], 1);
        col[p] = (int)e.x;
    }
}

// ============================ scans (unchanged) ============================
__global__ void k_scanA(const int* __restrict__ cnt, int* __restrict__ outv,
                        int* __restrict__ bsum) {
    __shared__ int sh[256];
    int t = threadIdx.x;
    int base = blockIdx.x * 1024 + t * 4;
    int v0=0,v1=0,v2=0,v3=0;
    if (base+0 < N_NODES) v0 = cnt[base+0];
    if (base+1 < N_NODES) v1 = cnt[base+1];
    if (base+2 < N_NODES) v2 = cnt[base+2];
    if (base+3 < N_NODES) v3 = cnt[base+3];
    int s = v0+v1+v2+v3;
    sh[t] = s; __syncthreads();
    for (int off = 1; off < 256; off <<= 1) {
        int tmp = (t >= off) ? sh[t-off] : 0;
        __syncthreads();
        sh[t] += tmp;
        __syncthreads();
    }
    int excl = sh[t] - s;
    if (t == 255) bsum[blockIdx.x] = sh[255];
    int run = excl;
    if (base+0 < N_NODES) { outv[base+0] = run; run += v0; }
    if (base+1 < N_NODES) { outv[base+1] = run; run += v1; }
    if (base+2 < N_NODES) { outv[base+2] = run; run += v2; }
    if (base+3 < N_NODES) { outv[base+3] = run; run += v3; }
}

__global__ void k_scanB(int* __restrict__ bsum, int* __restrict__ row_ptr) {
    if (threadIdx.x == 0 && blockIdx.x == 0) {
        int run = 0;
        for (int i = 0; i < 98; ++i) { int v = bsum[i]; bsum[i] = run; run += v; }
        row_ptr[N_NODES] = run;
    }
}

__global__ void k_scanC(int* __restrict__ row_ptr, const int* __restrict__ bsum,
                        int* __restrict__ cursor) {
    int i = blockIdx.x * 256 + threadIdx.x;
    if (i < N_NODES) {
        int v = row_ptr[i] + bsum[i >> 10];
        row_ptr[i] = v;
        cursor[i]  = v;
    }
}

// ============================ dtype prep ============================
__global__ void k_cvt_x(const float* __restrict__ x, unsigned short* __restrict__ xb) {
    int idx = blockIdx.x * 256 + threadIdx.x;
    float4 v = ((const float4*)x)[idx];
    ushort4 o;
    o.x = f2bf(v.x); o.y = f2bf(v.y); o.z = f2bf(v.z); o.w = f2bf(v.w);
    ((ushort4*)xb)[idx] = o;
}

__global__ void k_prep_w(const float* __restrict__ W0, const float* __restrict__ W1,
                         const float* __restrict__ W2, const float* __restrict__ W3,
                         unsigned short* __restrict__ Wt) {
    const float* Ws[4] = {W0, W1, W2, W3};
    const float* W = Ws[blockIdx.y];
    unsigned short* o = Wt + blockIdx.y * (DIM * DIM);
    int idx = blockIdx.x * 256 + threadIdx.x;
    int n = idx >> 7, k = idx & 127;
    o[idx] = f2bf(W[k * DIM + n]);
}

// ============================ Aggregation (bf16, unroll 2/half) ============================
__global__ void k_agg(const unsigned short* __restrict__ X,
                      unsigned short* __restrict__ Out,
                      const int* __restrict__ row_ptr, const int* __restrict__ col) {
    int wid = (blockIdx.x * 256 + threadIdx.x) >> 6;
    if (wid >= N_NODES) return;
    int lane = threadIdx.x & 63;
    int half = lane >> 5, m = lane & 31;
    const ushort4* X4 = (const ushort4*)X;

    float a0=0.f,a1=0.f,a2=0.f,a3=0.f;      // acc set 0
    float c0=0.f,c1=0.f,c2=0.f,c3=0.f;      // acc set 1
    if (half == 0) {
        ushort4 sv = X4[(size_t)wid * 32 + m];
        a0 = bf2f(sv.x); a1 = bf2f(sv.y); a2 = bf2f(sv.z); a3 = bf2f(sv.w);
    }
    int s = row_ptr[wid], e = row_ptr[wid + 1];
    int p = s + half;
    for (; p + 2 < e; p += 4) {
        int n0 = col[p], n1 = col[p + 2];
        ushort4 v0 = X4[(size_t)n0 * 32 + m];
        ushort4 v1 = X4[(size_t)n1 * 32 + m];
        a0 += bf2f(v0.x); a1 += bf2f(v0.y); a2 += bf2f(v0.z); a3 += bf2f(v0.w);
        c0 += bf2f(v1.x); c1 += bf2f(v1.y); c2 += bf2f(v1.z); c3 += bf2f(v1.w);
    }
    if (p < e) {
        ushort4 v = X4[(size_t)col[p] * 32 + m];
        a0 += bf2f(v.x); a1 += bf2f(v.y); a2 += bf2f(v.z); a3 += bf2f(v.w);
    }
    a0 += c0; a1 += c1; a2 += c2; a3 += c3;
    a0 += __shfl_xor(a0, 32);
    a1 += __shfl_xor(a1, 32);
    a2 += __shfl_xor(a2, 32);
    a3 += __shfl_xor(a3, 32);
    if (half == 0) {
        ushort4 o;
        o.x = f2bf(a0); o.y = f2bf(a1); o.z = f2bf(a2); o.w = f2bf(a3);
        ((ushort4*)Out)[(size_t)wid * 32 + m] = o;
    }
}

// ============================ MFMA GEMM [N,128] @ [128,128] ============================
// 128 rows/block, 256 threads (4 waves), wave handles 32 rows x 128 cols.
// Swapped operands: W-fragment is the M (row/reg) operand -> lane holds 4
// CONSECUTIVE output channels of one node -> 8B vector stores.
template<bool BN_LOAD, bool STATS, bool RELU_ST>
__global__ __launch_bounds__(256)
void k_gemm(const unsigned short* __restrict__ In, unsigned short* __restrict__ Out,
            const unsigned short* __restrict__ Wt, const float* __restrict__ bias,
            const float* __restrict__ scale, const float* __restrict__ shift,
            float* __restrict__ stat_sum, float* __restrict__ stat_sq) {
    __shared__ __align__(16) unsigned short sA[128][136];   // node rows
    __shared__ __align__(16) unsigned short sB[128][136];   // Wt[n][k]
    __shared__ float s_sum[128], s_sq[128];

    int t  = threadIdx.x;
    int r0 = blockIdx.x * 128;

    if (STATS && t < 128) { s_sum[t] = 0.f; s_sq[t] = 0.f; }

    #pragma unroll
    for (int u = 0; u < 8; ++u) {
        int f   = u * 256 + t;
        int row = f >> 4, kq = f & 15;
        int gr  = r0 + row;
        short8 v = {};
        if (gr < N_NODES) v = *(const short8*)(In + (size_t)gr * 128 + kq * 8);
        if (BN_LOAD) {
            #pragma unroll
            for (int j = 0; j < 8; ++j) {
                int k = kq * 8 + j;
                float fv = bf2f((unsigned short)v[j]);
                fv = fmaxf(fv * scale[k] + shift[k], 0.f);
                v[j] = (short)f2bf(fv);
            }
        }
        *(short8*)&sA[row][kq * 8] = v;
    }
    #pragma unroll
    for (int u = 0; u < 8; ++u) {
        int f = u * 256 + t;
        int n = f >> 4, kq = f & 15;
        *(short8*)&sB[n][kq * 8] = *(const short8*)(Wt + n * 128 + kq * 8);
    }
    __syncthreads();

    int wave = t >> 6;
    int lane = t & 63;
    int m = lane & 15;
    int q = lane >> 4;

    floatx4 acc[2][8] = {};
    #pragma unroll
    for (int kc = 0; kc < 128; kc += 32) {
        short8 n0 = *(const short8*)&sA[wave * 32 + m     ][kc + q * 8];
        short8 n1 = *(const short8*)&sA[wave * 32 + 16 + m][kc + q * 8];
        #pragma unroll
        for (int c = 0; c < 8; ++c) {
            short8 wf = *(const short8*)&sB[c * 16 + m][kc + q * 8];
            acc[0][c] = __builtin_amdgcn_mfma_f32_16x16x32_bf16(wf, n0, acc[0][c], 0, 0, 0);
            acc[1][c] = __builtin_amdgcn_mfma_f32_16x16x32_bf16(wf, n1, acc[1][c], 0, 0, 0);
        }
    }

    // D[ch = c*16 + q*4 + r][node = wave*32 + h*16 + m]
    #pragma unroll
    for (int c = 0; c < 8; ++c) {
        int ch0 = c * 16 + q * 4;
        float4 bv = *(const float4*)(bias + ch0);
        #pragma unroll
        for (int h = 0; h < 2; ++h) {
            int node = r0 + wave * 32 + h * 16 + m;
            if (node < N_NODES) {
                float v0 = acc[h][c][0] + bv.x;
                float v1 = acc[h][c][1] + bv.y;
                float v2 = acc[h][c][2] + bv.z;
                float v3 = acc[h][c][3] + bv.w;
                if (RELU_ST) {
                    v0 = fmaxf(v0, 0.f); v1 = fmaxf(v1, 0.f);
                    v2 = fmaxf(v2, 0.f); v3 = fmaxf(v3, 0.f);
                }
                ushort4 o;
                o.x = f2bf(v0); o.y = f2bf(v1); o.z = f2bf(v2); o.w = f2bf(v3);
                *(ushort4*)(Out + (size_t)node * 128 + ch0) = o;
                if (STATS) {
                    atomicAdd(&s_sum[ch0+0], v0); atomicAdd(&s_sq[ch0+0], v0*v0);
                    atomicAdd(&s_sum[ch0+1], v1); atomicAdd(&s_sq[ch0+1], v1*v1);
                    atomicAdd(&s_sum[ch0+2], v2); atomicAdd(&s_sq[ch0+2], v2*v2);
                    atomicAdd(&s_sum[ch0+3], v3); atomicAdd(&s_sq[ch0+3], v3*v3);
                }
            }
        }
    }
    if (STATS) {
        __syncthreads();
        if (t < 128) {
            atomicAdd(&stat_sum[t], s_sum[t]);
            atomicAdd(&stat_sq [t], s_sq[t]);
        }
    }
}

__global__ void k_bnfin(const float* __restrict__ sum, const float* __restrict__ sq,
                        const float* __restrict__ gamma, const float* __restrict__ beta,
                        float* __restrict__ scale, float* __restrict__ shift) {
    int c = threadIdx.x;
    if (c < DIM) {
        float m   = sum[c] * (1.0f / N_NODES);
        float var = sq[c] * (1.0f / N_NODES) - m * m;
        float inv = rsqrtf(var + BN_EPS);
        float sc  = gamma[c] * inv;
        scale[c] = sc;
        shift[c] = beta[c] - m * sc;
    }
}

// ============================ Pooling ============================
#define POOL_BLOCKS 512
#define POOL_CHUNK  196
__global__ void k_pool(const unsigned short* __restrict__ h, const int* __restrict__ batch,
                       float* __restrict__ pooled) {
    int c  = threadIdx.x;
    int n0 = blockIdx.x * POOL_CHUNK;
    if (n0 >= N_NODES) return;
    int n1 = min(n0 + POOL_CHUNK, N_NODES);
    int g = batch[n0];
    float acc = 0.f;
    for (int i = n0; i < n1; ++i) {
        int gi = batch[i];
        if (gi != g) { atomicAdd(&pooled[g * DIM + c], acc); acc = 0.f; g = gi; }
        acc += bf2f(h[(size_t)i * DIM + c]);
    }
    atomicAdd(&pooled[g * DIM + c], acc);
}

// ============================ Readout ============================
__global__ void k_readout1(const float* __restrict__ pooled, const float* __restrict__ W,
                           const float* __restrict__ b, float* __restrict__ r1) {
    int idx = blockIdx.x * 256 + threadIdx.x;
    int g = idx >> 7, c = idx & 127;
    float s = b[c];
    const float* p = pooled + g * DIM;
    #pragma unroll 8
    for (int k = 0; k < DIM; ++k) s += p[k] * W[k * DIM + c];
    r1[idx] = fmaxf(s, 0.f);
}

__global__ void k_readout2(const float* __restrict__ r1, const float* __restrict__ W,
                           const float* __restrict__ b, float* __restrict__ out) {
    int idx = blockIdx.x * 256 + threadIdx.x;
    if (idx >= NUM_GRAPHS * OUT_CH) return;
    int g = idx / OUT_CH, c = idx % OUT_CH;
    float s = b[c];
    const float* r = r1 + g * DIM;
    #pragma unroll 8
    for (int k = 0; k < DIM; ++k) s += r[k] * W[k * OUT_CH + c];
    out[idx] = s;
}

// ============================ Launch ============================
extern "C" void kernel_launch(void* const* d_in, const int* in_sizes, int n_in,
                              void* d_out, int out_size, void* d_ws, size_t ws_size,
                              hipStream_t stream) {
    const float* x   = (const float*)d_in[0];
    const int*   ei  = (const int*)d_in[1];
    const int*   bat = (const int*)d_in[2];
    const float* W1a = (const float*)d_in[3];
    const float* b1a = (const float*)d_in[4];
    const float* ga  = (const float*)d_in[5];
    const float* ba  = (const float*)d_in[6];
    const float* W2a = (const float*)d_in[7];
    const float* b2a = (const float*)d_in[8];
    const float* W1b = (const float*)d_in[9];
    const float* b1b = (const float*)d_in[10];
    const float* gb  = (const float*)d_in[11];
    const float* bbt = (const float*)d_in[12];
    const float* W2b = (const float*)d_in[13];
    const float* b2b = (const float*)d_in[14];
    const float* Wl1 = (const float*)d_in[15];
    const float* bl1 = (const float*)d_in[16];
    const float* Wl2 = (const float*)d_in[17];
    const float* bl2 = (const float*)d_in[18];
    float* out = (float*)d_out;

    const int* src = ei;
    const int* dst = ei + N_EDGES;

    char* w = (char*)d_ws;
    size_t off = 0;
    auto alloc = [&](size_t bytes) -> char* {
        char* p = w + off; off += (bytes + 255) & ~(size_t)255; return p;
    };
    unsigned short* xb   = (unsigned short*)alloc((size_t)N_NODES * DIM * 2);
    unsigned short* nb0  = (unsigned short*)alloc((size_t)N_NODES * DIM * 2);
    unsigned short* nb1  = (unsigned short*)alloc((size_t)N_NODES * DIM * 2);
    unsigned short* Wtb  = (unsigned short*)alloc((size_t)4 * DIM * DIM * 2);
    uint2* pairs   = (uint2*)alloc((size_t)NB * CAP * 8);
    int*   row_ptr = (int*)  alloc((size_t)(N_NODES + 1) * 4);
    int*   cnt     = (int*)  alloc((size_t)(NB * 1024) * 4);
    int*   cursor  = (int*)  alloc((size_t)N_NODES * 4);
    int*   col     = (int*)  alloc((size_t)N_EDGES * 4);
    int*   gcur    = (int*)  alloc(NB * 4);
    int*   bsum    = (int*)  alloc(98 * 4);
    float* ssumA   = (float*)alloc(DIM * 4);
    float* ssqA    = (float*)alloc(DIM * 4);
    float* ssumB   = (float*)alloc(DIM * 4);
    float* ssqB    = (float*)alloc(DIM * 4);
    float* scale   = (float*)alloc(DIM * 4);
    float* shift   = (float*)alloc(DIM * 4);
    float* pooled  = (float*)alloc((size_t)NUM_GRAPHS * DIM * 4);
    float* r1      = (float*)alloc((size_t)NUM_GRAPHS * DIM * 4);

    hipMemsetAsync(gcur,  0, NB * 4, stream);
    hipMemsetAsync(cnt,   0, (size_t)(NB * 1024) * 4, stream);
    hipMemsetAsync(ssumA, 0, DIM * 4 * 4, stream);   // ssumA/ssqA/ssumB/ssqB contiguous
    hipMemsetAsync(pooled,0, (size_t)NUM_GRAPHS * DIM * 4, stream);

    // CSR build via bucket partition
    k_bucket<<<(N_EDGES + 4095) / 4096, 256, 0, stream>>>(src, dst, gcur, pairs);
    k_count2<<<NB * SLICES, 256, 0, stream>>>(pairs, gcur, cnt);
    k_scanA<<<98, 256, 0, stream>>>(cnt, row_ptr, bsum);
    k_scanB<<<1, 64, 0, stream>>>(bsum, row_ptr);
    k_scanC<<<(N_NODES + 255) / 256, 256, 0, stream>>>(row_ptr, bsum, cursor);
    k_fill2<<<NB * SLICES, 256, 0, stream>>>(pairs, gcur, cursor, col);

    // dtype prep
    k_cvt_x<<<(N_NODES * DIM / 4) / 256, 256, 0, stream>>>(x, xb);
    k_prep_w<<<dim3(64, 4), 256, 0, stream>>>(W1a, W2a, W1b, W2b, Wtb);
    const unsigned short* Wt1a = Wtb;
    const unsigned short* Wt2a = Wtb + DIM * DIM;
    const unsigned short* Wt1b = Wtb + 2 * DIM * DIM;
    const unsigned short* Wt2b = Wtb + 3 * DIM * DIM;

    int agg_blocks  = (N_NODES * 64) / 256;
    int gemm_blocks = (N_NODES + 127) / 128;

    // conv1
    k_agg<<<agg_blocks, 256, 0, stream>>>(xb, nb0, row_ptr, col);
    k_gemm<false, true, false><<<gemm_blocks, 256, 0, stream>>>(nb0, nb1, Wt1a, b1a,
                                                                nullptr, nullptr, ssumA, ssqA);
    k_bnfin<<<1, 128, 0, stream>>>(ssumA, ssqA, ga, ba, scale, shift);
    k_gemm<true, false, true><<<gemm_blocks, 256, 0, stream>>>(nb1, nb0, Wt2a, b2a,
                                                               scale, shift, nullptr, nullptr);
    // conv2
    k_agg<<<agg_blocks, 256, 0, stream>>>(nb0, nb1, row_ptr, col);
    k_gemm<false, true, false><<<gemm_blocks, 256, 0, stream>>>(nb1, nb0, Wt1b, b1b,
                                                                nullptr, nullptr, ssumB, ssqB);
    k_bnfin<<<1, 128, 0, stream>>>(ssumB, ssqB, gb, bbt, scale, shift);
    k_gemm<true, false, true><<<gemm_blocks, 256, 0, stream>>>(nb0, nb1, Wt2b, b2b,
                                                               scale, shift, nullptr, nullptr);
    // readout
    k_pool<<<POOL_BLOCKS, 128, 0, stream>>>(nb1, bat, pooled);
    k_readout1<<<(NUM_GRAPHS * DIM) / 256, 256, 0, stream>>>(pooled, Wl1, bl1, r1);
    k_readout2<<<(NUM_GRAPHS * OUT_CH + 255) / 256, 256, 0, stream>>>(r1, Wl2, bl2, out);
}

// Round 4
// 536.282 us; speedup vs baseline: 1.7379x; 1.7379x over previous
//
#include <hip/hip_runtime.h>

#define N_NODES    100000
#define N_EDGES    1600000
#define DIM        128
#define OUT_CH     10
#define NUM_GRAPHS 128
#define BN_EPS     1e-5f

// bucket partition params
#define BSHIFT   10
#define NB       98          // ceil(100000 / 1024)
#define CAP      24576
#define SLICES   3
#define SLICE_SLOTS 8192

typedef __attribute__((ext_vector_type(8))) short short8;
typedef __attribute__((ext_vector_type(4))) float floatx4;

__device__ inline float bf2f(unsigned short u) {
    union { unsigned i; float f; } v; v.i = (unsigned)u << 16; return v.f;
}
__device__ inline unsigned short f2bf(float f) {
    union { float f; unsigned i; } v; v.f = f;
    unsigned r = (v.i + 0x7fffu + ((v.i >> 16) & 1u)) >> 16;
    return (unsigned short)r;
}

// ===================== bucket partition (src,dst) by dst>>10 =====================
__global__ __launch_bounds__(256)
void k_bucket(const int* __restrict__ src, const int* __restrict__ dst,
              int* __restrict__ gcur, uint2* __restrict__ pairs) {
    __shared__ int h[NB];
    int t = threadIdx.x;
    if (t < NB) h[t] = 0;
    __syncthreads();
    int base = blockIdx.x * 4096;
    #pragma unroll
    for (int i = 0; i < 16; ++i) {
        int idx = base + i * 256 + t;
        if (idx < N_EDGES) atomicAdd(&h[dst[idx] >> BSHIFT], 1);
    }
    __syncthreads();
    if (t < NB) h[t] = atomicAdd(&gcur[t], h[t]);
    __syncthreads();
    #pragma unroll
    for (int i = 0; i < 16; ++i) {
        int idx = base + i * 256 + t;
        if (idx < N_EDGES) {
            int d = dst[idx];
            int b = d >> BSHIFT;
            int pos = atomicAdd(&h[b], 1);
            if (pos < CAP) pairs[(size_t)b * CAP + pos] = make_uint2((unsigned)src[idx], (unsigned)d);
        }
    }
}

__global__ __launch_bounds__(256)
void k_count2(const uint2* __restrict__ pairs, const int* __restrict__ gcur,
              int* __restrict__ cnt) {
    __shared__ int lc[1024];
    int bi = blockIdx.x / SLICES, s = blockIdx.x % SLICES;
    int t = threadIdx.x;
    for (int i = t; i < 1024; i += 256) lc[i] = 0;
    __syncthreads();
    int n  = min(gcur[bi], CAP);
    int lo = s * SLICE_SLOTS, hi = min(lo + SLICE_SLOTS, n);
    const uint2* P = pairs + (size_t)bi * CAP;
    for (int i = lo + t; i < hi; i += 256)
        atomicAdd(&lc[P[i].y & 1023], 1);
    __syncthreads();
    int nb0 = bi << BSHIFT;
    for (int i = t; i < 1024; i += 256)
        if (lc[i] > 0) atomicAdd(&cnt[nb0 + i], lc[i]);
}

__global__ __launch_bounds__(256)
void k_fill2(const uint2* __restrict__ pairs, const int* __restrict__ gcur,
             int* __restrict__ cursor, int* __restrict__ col) {
    __shared__ int lc[1024];
    __shared__ int lb[1024];
    int bi = blockIdx.x / SLICES, s = blockIdx.x % SLICES;
    int t = threadIdx.x;
    for (int i = t; i < 1024; i += 256) lc[i] = 0;
    __syncthreads();
    int n  = min(gcur[bi], CAP);
    int lo = s * SLICE_SLOTS, hi = min(lo + SLICE_SLOTS, n);
    const uint2* P = pairs + (size_t)bi * CAP;
    int nb0 = bi << BSHIFT;
    for (int i = lo + t; i < hi; i += 256)
        atomicAdd(&lc[P[i].y & 1023], 1);
    __syncthreads();
    for (int i = t; i < 1024; i += 256)
        lb[i] = (lc[i] > 0) ? atomicAdd(&cursor[nb0 + i], lc[i]) : 0;
    __syncthreads();
    for (int i = lo + t; i < hi; i += 256) {
        uint2 e = P[i];
        int p = atomicAdd(&lb[e.y & 1023], 1);
        col[p] = (int)e.x;
    }
}

// ============================ scans ============================
__global__ void k_scanA(const int* __restrict__ cnt, int* __restrict__ outv,
                        int* __restrict__ bsum) {
    __shared__ int sh[256];
    int t = threadIdx.x;
    int base = blockIdx.x * 1024 + t * 4;
    int v0=0,v1=0,v2=0,v3=0;
    if (base+0 < N_NODES) v0 = cnt[base+0];
    if (base+1 < N_NODES) v1 = cnt[base+1];
    if (base+2 < N_NODES) v2 = cnt[base+2];
    if (base+3 < N_NODES) v3 = cnt[base+3];
    int s = v0+v1+v2+v3;
    sh[t] = s; __syncthreads();
    for (int off = 1; off < 256; off <<= 1) {
        int tmp = (t >= off) ? sh[t-off] : 0;
        __syncthreads();
        sh[t] += tmp;
        __syncthreads();
    }
    int excl = sh[t] - s;
    if (t == 255) bsum[blockIdx.x] = sh[255];
    int run = excl;
    if (base+0 < N_NODES) { outv[base+0] = run; run += v0; }
    if (base+1 < N_NODES) { outv[base+1] = run; run += v1; }
    if (base+2 < N_NODES) { outv[base+2] = run; run += v2; }
    if (base+3 < N_NODES) { outv[base+3] = run; run += v3; }
}

__global__ void k_scanB(int* __restrict__ bsum, int* __restrict__ row_ptr) {
    if (threadIdx.x == 0 && blockIdx.x == 0) {
        int run = 0;
        for (int i = 0; i < 98; ++i) { int v = bsum[i]; bsum[i] = run; run += v; }
        row_ptr[N_NODES] = run;
    }
}

__global__ void k_scanC(int* __restrict__ row_ptr, const int* __restrict__ bsum,
                        int* __restrict__ cursor) {
    int i = blockIdx.x * 256 + threadIdx.x;
    if (i < N_NODES) {
        int v = row_ptr[i] + bsum[i >> 10];
        row_ptr[i] = v;
        cursor[i]  = v;
    }
}

// ============================ dtype prep ============================
__global__ void k_cvt_x(const float* __restrict__ x, unsigned short* __restrict__ xb) {
    int idx = blockIdx.x * 256 + threadIdx.x;
    float4 v = ((const float4*)x)[idx];
    ushort4 o;
    o.x = f2bf(v.x); o.y = f2bf(v.y); o.z = f2bf(v.z); o.w = f2bf(v.w);
    ((ushort4*)xb)[idx] = o;
}

__global__ void k_prep_w(const float* __restrict__ W0, const float* __restrict__ W1,
                         const float* __restrict__ W2, const float* __restrict__ W3,
                         unsigned short* __restrict__ Wt) {
    const float* Ws[4] = {W0, W1, W2, W3};
    const float* W = Ws[blockIdx.y];
    unsigned short* o = Wt + blockIdx.y * (DIM * DIM);
    int idx = blockIdx.x * 256 + threadIdx.x;
    int n = idx >> 7, k = idx & 127;
    o[idx] = f2bf(W[k * DIM + n]);
}

// ============================ Aggregation (bf16, 4 gathers in flight/half) ============================
__global__ void k_agg(const unsigned short* __restrict__ X,
                      unsigned short* __restrict__ Out,
                      const int* __restrict__ row_ptr, const int* __restrict__ col) {
    int wid = (blockIdx.x * 256 + threadIdx.x) >> 6;
    if (wid >= N_NODES) return;
    int lane = threadIdx.x & 63;
    int half = lane >> 5, m = lane & 31;
    const ushort4* X4 = (const ushort4*)X;

    float a0=0.f,a1=0.f,a2=0.f,a3=0.f;
    float c0=0.f,c1=0.f,c2=0.f,c3=0.f;
    if (half == 0) {
        ushort4 sv = X4[(size_t)wid * 32 + m];
        a0 = bf2f(sv.x); a1 = bf2f(sv.y); a2 = bf2f(sv.z); a3 = bf2f(sv.w);
    }
    int s = row_ptr[wid], e = row_ptr[wid + 1];
    int p = s + half;
    for (; p + 6 < e; p += 8) {
        int n0 = col[p], n1 = col[p + 2], n2 = col[p + 4], n3 = col[p + 6];
        ushort4 v0 = X4[(size_t)n0 * 32 + m];
        ushort4 v1 = X4[(size_t)n1 * 32 + m];
        ushort4 v2 = X4[(size_t)n2 * 32 + m];
        ushort4 v3 = X4[(size_t)n3 * 32 + m];
        a0 += bf2f(v0.x); a1 += bf2f(v0.y); a2 += bf2f(v0.z); a3 += bf2f(v0.w);
        c0 += bf2f(v1.x); c1 += bf2f(v1.y); c2 += bf2f(v1.z); c3 += bf2f(v1.w);
        a0 += bf2f(v2.x); a1 += bf2f(v2.y); a2 += bf2f(v2.z); a3 += bf2f(v2.w);
        c0 += bf2f(v3.x); c1 += bf2f(v3.y); c2 += bf2f(v3.z); c3 += bf2f(v3.w);
    }
    for (; p < e; p += 2) {
        ushort4 v = X4[(size_t)col[p] * 32 + m];
        a0 += bf2f(v.x); a1 += bf2f(v.y); a2 += bf2f(v.z); a3 += bf2f(v.w);
    }
    a0 += c0; a1 += c1; a2 += c2; a3 += c3;
    a0 += __shfl_xor(a0, 32);
    a1 += __shfl_xor(a1, 32);
    a2 += __shfl_xor(a2, 32);
    a3 += __shfl_xor(a3, 32);
    if (half == 0) {
        ushort4 o;
        o.x = f2bf(a0); o.y = f2bf(a1); o.z = f2bf(a2); o.w = f2bf(a3);
        ((ushort4*)Out)[(size_t)wid * 32 + m] = o;
    }
}

// ============================ MFMA GEMM [N,128] @ [128,128] ============================
// 128 rows/block, 4 waves, swapped operands (W = M operand) -> ushort4 stores.
// No BN-stats here (separate k_stats pass).
template<bool BN_LOAD, bool RELU_ST>
__global__ __launch_bounds__(256)
void k_gemm(const unsigned short* __restrict__ In, unsigned short* __restrict__ Out,
            const unsigned short* __restrict__ Wt, const float* __restrict__ bias,
            const float* __restrict__ scale, const float* __restrict__ shift) {
    __shared__ __align__(16) unsigned short sA[128][136];
    __shared__ __align__(16) unsigned short sB[128][136];

    int t  = threadIdx.x;
    int r0 = blockIdx.x * 128;

    #pragma unroll
    for (int u = 0; u < 8; ++u) {
        int f   = u * 256 + t;
        int row = f >> 4, kq = f & 15;
        int gr  = r0 + row;
        short8 v = {};
        if (gr < N_NODES) v = *(const short8*)(In + (size_t)gr * 128 + kq * 8);
        if (BN_LOAD) {
            #pragma unroll
            for (int j = 0; j < 8; ++j) {
                int k = kq * 8 + j;
                float fv = bf2f((unsigned short)v[j]);
                fv = fmaxf(fv * scale[k] + shift[k], 0.f);
                v[j] = (short)f2bf(fv);
            }
        }
        *(short8*)&sA[row][kq * 8] = v;
    }
    #pragma unroll
    for (int u = 0; u < 8; ++u) {
        int f = u * 256 + t;
        int n = f >> 4, kq = f & 15;
        *(short8*)&sB[n][kq * 8] = *(const short8*)(Wt + n * 128 + kq * 8);
    }
    __syncthreads();

    int wave = t >> 6;
    int lane = t & 63;
    int m = lane & 15;
    int q = lane >> 4;

    floatx4 acc[2][8] = {};
    #pragma unroll
    for (int kc = 0; kc < 128; kc += 32) {
        short8 n0 = *(const short8*)&sA[wave * 32 + m     ][kc + q * 8];
        short8 n1 = *(const short8*)&sA[wave * 32 + 16 + m][kc + q * 8];
        #pragma unroll
        for (int c = 0; c < 8; ++c) {
            short8 wf = *(const short8*)&sB[c * 16 + m][kc + q * 8];
            acc[0][c] = __builtin_amdgcn_mfma_f32_16x16x32_bf16(wf, n0, acc[0][c], 0, 0, 0);
            acc[1][c] = __builtin_amdgcn_mfma_f32_16x16x32_bf16(wf, n1, acc[1][c], 0, 0, 0);
        }
    }

    // D[ch = c*16 + q*4 + r][node = wave*32 + h*16 + m]
    #pragma unroll
    for (int c = 0; c < 8; ++c) {
        int ch0 = c * 16 + q * 4;
        float4 bv = *(const float4*)(bias + ch0);
        #pragma unroll
        for (int h = 0; h < 2; ++h) {
            int node = r0 + wave * 32 + h * 16 + m;
            if (node < N_NODES) {
                float v0 = acc[h][c][0] + bv.x;
                float v1 = acc[h][c][1] + bv.y;
                float v2 = acc[h][c][2] + bv.z;
                float v3 = acc[h][c][3] + bv.w;
                if (RELU_ST) {
                    v0 = fmaxf(v0, 0.f); v1 = fmaxf(v1, 0.f);
                    v2 = fmaxf(v2, 0.f); v3 = fmaxf(v3, 0.f);
                }
                ushort4 o;
                o.x = f2bf(v0); o.y = f2bf(v1); o.z = f2bf(v2); o.w = f2bf(v3);
                *(ushort4*)(Out + (size_t)node * 128 + ch0) = o;
            }
        }
    }
}

// ============================ BN stats pass ============================
#define ST_BLOCKS 250
#define ST_ROWS   400
__global__ __launch_bounds__(256)
void k_stats(const unsigned short* __restrict__ H,
             float* __restrict__ ssum, float* __restrict__ ssq) {
    __shared__ float rs[8][128];
    __shared__ float rq[8][128];
    int t  = threadIdx.x;
    int cq = t & 31;          // channel quad
    int r  = t >> 5;          // row subgroup 0..7
    int row0 = blockIdx.x * ST_ROWS;
    float s0=0,s1=0,s2=0,s3=0,q0=0,q1=0,q2=0,q3=0;
    for (int i = r; i < ST_ROWS; i += 8) {
        ushort4 v = *(const ushort4*)(H + (size_t)(row0 + i) * 128 + cq * 4);
        float f0=bf2f(v.x), f1=bf2f(v.y), f2=bf2f(v.z), f3=bf2f(v.w);
        s0+=f0; s1+=f1; s2+=f2; s3+=f3;
        q0+=f0*f0; q1+=f1*f1; q2+=f2*f2; q3+=f3*f3;
    }
    rs[r][cq*4+0]=s0; rs[r][cq*4+1]=s1; rs[r][cq*4+2]=s2; rs[r][cq*4+3]=s3;
    rq[r][cq*4+0]=q0; rq[r][cq*4+1]=q1; rq[r][cq*4+2]=q2; rq[r][cq*4+3]=q3;
    __syncthreads();
    if (t < 128) {
        float a = 0.f, b = 0.f;
        #pragma unroll
        for (int j = 0; j < 8; ++j) { a += rs[j][t]; b += rq[j][t]; }
        atomicAdd(&ssum[t], a);
        atomicAdd(&ssq [t], b);
    }
}

__global__ void k_bnfin(const float* __restrict__ sum, const float* __restrict__ sq,
                        const float* __restrict__ gamma, const float* __restrict__ beta,
                        float* __restrict__ scale, float* __restrict__ shift) {
    int c = threadIdx.x;
    if (c < DIM) {
        float m   = sum[c] * (1.0f / N_NODES);
        float var = sq[c] * (1.0f / N_NODES) - m * m;
        float inv = rsqrtf(var + BN_EPS);
        float sc  = gamma[c] * inv;
        scale[c] = sc;
        shift[c] = beta[c] - m * sc;
    }
}

// ============================ Pooling ============================
#define POOL_BLOCKS 512
#define POOL_CHUNK  196
__global__ void k_pool(const unsigned short* __restrict__ h, const int* __restrict__ batch,
                       float* __restrict__ pooled) {
    int c  = threadIdx.x;
    int n0 = blockIdx.x * POOL_CHUNK;
    if (n0 >= N_NODES) return;
    int n1 = min(n0 + POOL_CHUNK, N_NODES);
    int g = batch[n0];
    float acc = 0.f;
    for (int i = n0; i < n1; ++i) {
        int gi = batch[i];
        if (gi != g) { atomicAdd(&pooled[g * DIM + c], acc); acc = 0.f; g = gi; }
        acc += bf2f(h[(size_t)i * DIM + c]);
    }
    atomicAdd(&pooled[g * DIM + c], acc);
}

// ============================ Readout ============================
__global__ void k_readout1(const float* __restrict__ pooled, const float* __restrict__ W,
                           const float* __restrict__ b, float* __restrict__ r1) {
    int idx = blockIdx.x * 256 + threadIdx.x;
    int g = idx >> 7, c = idx & 127;
    float s = b[c];
    const float* p = pooled + g * DIM;
    #pragma unroll 8
    for (int k = 0; k < DIM; ++k) s += p[k] * W[k * DIM + c];
    r1[idx] = fmaxf(s, 0.f);
}

__global__ void k_readout2(const float* __restrict__ r1, const float* __restrict__ W,
                           const float* __restrict__ b, float* __restrict__ out) {
    int idx = blockIdx.x * 256 + threadIdx.x;
    if (idx >= NUM_GRAPHS * OUT_CH) return;
    int g = idx / OUT_CH, c = idx % OUT_CH;
    float s = b[c];
    const float* r = r1 + g * DIM;
    #pragma unroll 8
    for (int k = 0; k < DIM; ++k) s += r[k] * W[k * OUT_CH + c];
    out[idx] = s;
}

// ============================ Launch ============================
extern "C" void kernel_launch(void* const* d_in, const int* in_sizes, int n_in,
                              void* d_out, int out_size, void* d_ws, size_t ws_size,
                              hipStream_t stream) {
    const float* x   = (const float*)d_in[0];
    const int*   ei  = (const int*)d_in[1];
    const int*   bat = (const int*)d_in[2];
    const float* W1a = (const float*)d_in[3];
    const float* b1a = (const float*)d_in[4];
    const float* ga  = (const float*)d_in[5];
    const float* ba  = (const float*)d_in[6];
    const float* W2a = (const float*)d_in[7];
    const float* b2a = (const float*)d_in[8];
    const float* W1b = (const float*)d_in[9];
    const float* b1b = (const float*)d_in[10];
    const float* gb  = (const float*)d_in[11];
    const float* bbt = (const float*)d_in[12];
    const float* W2b = (const float*)d_in[13];
    const float* b2b = (const float*)d_in[14];
    const float* Wl1 = (const float*)d_in[15];
    const float* bl1 = (const float*)d_in[16];
    const float* Wl2 = (const float*)d_in[17];
    const float* bl2 = (const float*)d_in[18];
    float* out = (float*)d_out;

    const int* src = ei;
    const int* dst = ei + N_EDGES;

    char* w = (char*)d_ws;
    size_t off = 0;
    auto alloc = [&](size_t bytes) -> char* {
        char* p = w + off; off += (bytes + 255) & ~(size_t)255; return p;
    };
    unsigned short* xb   = (unsigned short*)alloc((size_t)N_NODES * DIM * 2);
    unsigned short* nb0  = (unsigned short*)alloc((size_t)N_NODES * DIM * 2);
    unsigned short* nb1  = (unsigned short*)alloc((size_t)N_NODES * DIM * 2);
    unsigned short* Wtb  = (unsigned short*)alloc((size_t)4 * DIM * DIM * 2);
    uint2* pairs   = (uint2*)alloc((size_t)NB * CAP * 8);
    int*   row_ptr = (int*)  alloc((size_t)(N_NODES + 1) * 4);
    int*   cnt     = (int*)  alloc((size_t)(NB * 1024) * 4);
    int*   cursor  = (int*)  alloc((size_t)N_NODES * 4);
    int*   col     = (int*)  alloc((size_t)N_EDGES * 4);
    int*   gcur    = (int*)  alloc(NB * 4);
    int*   bsum    = (int*)  alloc(98 * 4);
    float* ssumA   = (float*)alloc(DIM * 4);
    float* ssqA    = (float*)alloc(DIM * 4);
    float* ssumB   = (float*)alloc(DIM * 4);
    float* ssqB    = (float*)alloc(DIM * 4);
    float* scale   = (float*)alloc(DIM * 4);
    float* shift   = (float*)alloc(DIM * 4);
    float* pooled  = (float*)alloc((size_t)NUM_GRAPHS * DIM * 4);
    float* r1      = (float*)alloc((size_t)NUM_GRAPHS * DIM * 4);

    hipMemsetAsync(gcur,  0, NB * 4, stream);
    hipMemsetAsync(cnt,   0, (size_t)(NB * 1024) * 4, stream);
    hipMemsetAsync(ssumA, 0, DIM * 4 * 4, stream);   // ssumA/ssqA/ssumB/ssqB contiguous
    hipMemsetAsync(pooled,0, (size_t)NUM_GRAPHS * DIM * 4, stream);

    // CSR build via bucket partition
    k_bucket<<<(N_EDGES + 4095) / 4096, 256, 0, stream>>>(src, dst, gcur, pairs);
    k_count2<<<NB * SLICES, 256, 0, stream>>>(pairs, gcur, cnt);
    k_scanA<<<98, 256, 0, stream>>>(cnt, row_ptr, bsum);
    k_scanB<<<1, 64, 0, stream>>>(bsum, row_ptr);
    k_scanC<<<(N_NODES + 255) / 256, 256, 0, stream>>>(row_ptr, bsum, cursor);
    k_fill2<<<NB * SLICES, 256, 0, stream>>>(pairs, gcur, cursor, col);

    // dtype prep
    k_cvt_x<<<(N_NODES * DIM / 4) / 256, 256, 0, stream>>>(x, xb);
    k_prep_w<<<dim3(64, 4), 256, 0, stream>>>(W1a, W2a, W1b, W2b, Wtb);
    const unsigned short* Wt1a = Wtb;
    const unsigned short* Wt2a = Wtb + DIM * DIM;
    const unsigned short* Wt1b = Wtb + 2 * DIM * DIM;
    const unsigned short* Wt2b = Wtb + 3 * DIM * DIM;

    int agg_blocks  = (N_NODES * 64) / 256;
    int gemm_blocks = (N_NODES + 127) / 128;

    // conv1
    k_agg<<<agg_blocks, 256, 0, stream>>>(xb, nb0, row_ptr, col);
    k_gemm<false, false><<<gemm_blocks, 256, 0, stream>>>(nb0, nb1, Wt1a, b1a,
                                                          nullptr, nullptr);
    k_stats<<<ST_BLOCKS, 256, 0, stream>>>(nb1, ssumA, ssqA);
    k_bnfin<<<1, 128, 0, stream>>>(ssumA, ssqA, ga, ba, scale, shift);
    k_gemm<true, true><<<gemm_blocks, 256, 0, stream>>>(nb1, nb0, Wt2a, b2a,
                                                        scale, shift);
    // conv2
    k_agg<<<agg_blocks, 256, 0, stream>>>(nb0, nb1, row_ptr, col);
    k_gemm<false, false><<<gemm_blocks, 256, 0, stream>>>(nb1, nb0, Wt1b, b1b,
                                                          nullptr, nullptr);
    k_stats<<<ST_BLOCKS, 256, 0, stream>>>(nb0, ssumB, ssqB);
    k_bnfin<<<1, 128, 0, stream>>>(ssumB, ssqB, gb, bbt, scale, shift);
    k_gemm<true, true><<<gemm_blocks, 256, 0, stream>>>(nb0, nb1, Wt2b, b2b,
                                                        scale, shift);
    // readout
    k_pool<<<POOL_BLOCKS, 128, 0, stream>>>(nb1, bat, pooled);
    k_readout1<<<(NUM_GRAPHS * DIM) / 256, 256, 0, stream>>>(pooled, Wl1, bl1, r1);
    k_readout2<<<(NUM_GRAPHS * OUT_CH + 255) / 256, 256, 0, stream>>>(r1, Wl2, bl2, out);
}

// Round 5
// 526.288 us; speedup vs baseline: 1.7709x; 1.0190x over previous
//
#include <hip/hip_runtime.h>

#define N_NODES    100000
#define N_EDGES    1600000
#define DIM        128
#define OUT_CH     10
#define NUM_GRAPHS 128
#define BN_EPS     1e-5f

// bucket partition params (256 nodes/bucket)
#define BSHIFT   8
#define NB2      391         // ceil(100000 / 256)
#define CAP2     5120        // expected ~4092/bucket, +16 sigma

typedef __attribute__((ext_vector_type(8))) short short8;
typedef __attribute__((ext_vector_type(4))) float floatx4;

__device__ inline float bf2f(unsigned short u) {
    union { unsigned i; float f; } v; v.i = (unsigned)u << 16; return v.f;
}
__device__ inline unsigned short f2bf(float f) {
    union { float f; unsigned i; } v; v.f = f;
    unsigned r = (v.i + 0x7fffu + ((v.i >> 16) & 1u)) >> 16;
    return (unsigned short)r;
}

__device__ inline void async_cp16(const unsigned short* g, unsigned short* l) {
    __builtin_amdgcn_global_load_lds(
        (const __attribute__((address_space(1))) void*)g,
        (__attribute__((address_space(3))) void*)l, 16, 0, 0);
}

// ===================== bucket partition (src,dst) by dst>>8 =====================
__global__ __launch_bounds__(256)
void k_bucket(const int* __restrict__ src, const int* __restrict__ dst,
              int* __restrict__ gcur, uint2* __restrict__ pairs) {
    __shared__ int h[NB2];
    int t = threadIdx.x;
    for (int i = t; i < NB2; i += 256) h[i] = 0;
    __syncthreads();
    int base = blockIdx.x * 4096;
    #pragma unroll
    for (int i = 0; i < 16; ++i) {
        int idx = base + i * 256 + t;
        if (idx < N_EDGES) atomicAdd(&h[dst[idx] >> BSHIFT], 1);
    }
    __syncthreads();
    for (int i = t; i < NB2; i += 256) h[i] = atomicAdd(&gcur[i], h[i]);
    __syncthreads();
    #pragma unroll
    for (int i = 0; i < 16; ++i) {
        int idx = base + i * 256 + t;
        if (idx < N_EDGES) {
            int d = dst[idx];
            int b = d >> BSHIFT;
            int pos = atomicAdd(&h[b], 1);
            if (pos < CAP2) pairs[(size_t)b * CAP2 + pos] = make_uint2((unsigned)src[idx], (unsigned)d);
        }
    }
}

// exclusive scan of bucket sizes
__global__ void k_bscan(const int* __restrict__ gcur, int* __restrict__ bbase,
                        int* __restrict__ row_ptr) {
    __shared__ int sh[512];
    int t = threadIdx.x;
    int v = (t < NB2) ? min(gcur[t], CAP2) : 0;
    sh[t] = v; __syncthreads();
    for (int off = 1; off < 512; off <<= 1) {
        int tmp = (t >= off) ? sh[t - off] : 0;
        __syncthreads();
        sh[t] += tmp;
        __syncthreads();
    }
    if (t < NB2) bbase[t] = sh[t] - v;
    if (t == NB2 - 1) { bbase[NB2] = sh[t]; row_ptr[N_NODES] = sh[t]; }
}

// per-bucket: hist -> scan -> row_ptr + direct col placement
__global__ __launch_bounds__(256)
void k_csr(const uint2* __restrict__ pairs, const int* __restrict__ gcur,
           const int* __restrict__ bbase, int* __restrict__ row_ptr,
           int* __restrict__ col) {
    __shared__ int hist[256];
    __shared__ int cur[256];
    int bi = blockIdx.x, t = threadIdx.x;
    hist[t] = 0; __syncthreads();
    int n = min(gcur[bi], CAP2);
    const uint2* P = pairs + (size_t)bi * CAP2;
    for (int i = t; i < n; i += 256)
        atomicAdd(&hist[P[i].y & 255], 1);
    __syncthreads();
    int self = hist[t];
    cur[t] = self; __syncthreads();
    for (int off = 1; off < 256; off <<= 1) {
        int tmp = (t >= off) ? cur[t - off] : 0;
        __syncthreads();
        cur[t] += tmp;
        __syncthreads();
    }
    int excl = cur[t] - self;
    int base = bbase[bi];
    int node = (bi << 8) + t;
    if (node < N_NODES) row_ptr[node] = base + excl;
    __syncthreads();
    cur[t] = base + excl;
    __syncthreads();
    for (int i = t; i < n; i += 256) {
        uint2 e = P[i];
        int pos = atomicAdd(&cur[e.y & 255], 1);
        col[pos] = (int)e.x;
    }
}

// ============================ dtype prep ============================
__global__ void k_cvt_x(const float* __restrict__ x, unsigned short* __restrict__ xb) {
    int idx = blockIdx.x * 256 + threadIdx.x;
    float4 v = ((const float4*)x)[idx];
    ushort4 o;
    o.x = f2bf(v.x); o.y = f2bf(v.y); o.z = f2bf(v.z); o.w = f2bf(v.w);
    ((ushort4*)xb)[idx] = o;
}

__global__ void k_prep_w(const float* __restrict__ W0, const float* __restrict__ W1,
                         const float* __restrict__ W2, const float* __restrict__ W3,
                         unsigned short* __restrict__ Wt) {
    const float* Ws[4] = {W0, W1, W2, W3};
    const float* W = Ws[blockIdx.y];
    unsigned short* o = Wt + blockIdx.y * (DIM * DIM);
    int idx = blockIdx.x * 256 + threadIdx.x;
    int n = idx >> 7, k = idx & 127;
    o[idx] = f2bf(W[k * DIM + n]);
}

// ============================ Aggregation (bf16, 4 gathers in flight/half) ============================
__global__ void k_agg(const unsigned short* __restrict__ X,
                      unsigned short* __restrict__ Out,
                      const int* __restrict__ row_ptr, const int* __restrict__ col) {
    int wid = (blockIdx.x * 256 + threadIdx.x) >> 6;
    if (wid >= N_NODES) return;
    int lane = threadIdx.x & 63;
    int half = lane >> 5, m = lane & 31;
    const ushort4* X4 = (const ushort4*)X;

    float a0=0.f,a1=0.f,a2=0.f,a3=0.f;
    float c0=0.f,c1=0.f,c2=0.f,c3=0.f;
    if (half == 0) {
        ushort4 sv = X4[(size_t)wid * 32 + m];
        a0 = bf2f(sv.x); a1 = bf2f(sv.y); a2 = bf2f(sv.z); a3 = bf2f(sv.w);
    }
    int s = row_ptr[wid], e = row_ptr[wid + 1];
    int p = s + half;
    for (; p + 6 < e; p += 8) {
        int n0 = col[p], n1 = col[p + 2], n2 = col[p + 4], n3 = col[p + 6];
        ushort4 v0 = X4[(size_t)n0 * 32 + m];
        ushort4 v1 = X4[(size_t)n1 * 32 + m];
        ushort4 v2 = X4[(size_t)n2 * 32 + m];
        ushort4 v3 = X4[(size_t)n3 * 32 + m];
        a0 += bf2f(v0.x); a1 += bf2f(v0.y); a2 += bf2f(v0.z); a3 += bf2f(v0.w);
        c0 += bf2f(v1.x); c1 += bf2f(v1.y); c2 += bf2f(v1.z); c3 += bf2f(v1.w);
        a0 += bf2f(v2.x); a1 += bf2f(v2.y); a2 += bf2f(v2.z); a3 += bf2f(v2.w);
        c0 += bf2f(v3.x); c1 += bf2f(v3.y); c2 += bf2f(v3.z); c3 += bf2f(v3.w);
    }
    for (; p < e; p += 2) {
        ushort4 v = X4[(size_t)col[p] * 32 + m];
        a0 += bf2f(v.x); a1 += bf2f(v.y); a2 += bf2f(v.z); a3 += bf2f(v.w);
    }
    a0 += c0; a1 += c1; a2 += c2; a3 += c3;
    a0 += __shfl_xor(a0, 32);
    a1 += __shfl_xor(a1, 32);
    a2 += __shfl_xor(a2, 32);
    a3 += __shfl_xor(a3, 32);
    if (half == 0) {
        ushort4 o;
        o.x = f2bf(a0); o.y = f2bf(a1); o.z = f2bf(a2); o.w = f2bf(a3);
        ((ushort4*)Out)[(size_t)wid * 32 + m] = o;
    }
}

// ============================ MFMA GEMM, async staging + XOR swizzle ============================
// 128 rows/block, 4 waves. LDS unpadded [row][16 chunks of 16B], chunk
// placement swizzled: slot (row, p) holds global chunk (row, p ^ (row&7)).
// Swizzle applied on the global source address (DMA slot is lane-fixed).
template<bool RELU_ST>
__global__ __launch_bounds__(256)
void k_gemm(const unsigned short* __restrict__ In, unsigned short* __restrict__ Out,
            const unsigned short* __restrict__ Wt, const float* __restrict__ bias) {
    __shared__ __align__(16) unsigned short sA[128 * 128];
    __shared__ __align__(16) unsigned short sB[128 * 128];

    int t = threadIdx.x;
    int w = t >> 6, lane = t & 63;
    int r0 = blockIdx.x * 128;

    // A tile: 2048 chunks; wave w stages chunks [(w*8+u)*64 + lane]
    #pragma unroll
    for (int u = 0; u < 8; ++u) {
        int i = (w * 8 + u) * 64 + lane;
        int row = i >> 4, p = i & 15;
        int gr = r0 + row; if (gr >= N_NODES) gr = 0;   // clamp; masked at store
        const unsigned short* g = In + (size_t)gr * 128 + ((p ^ (row & 7)) << 3);
        async_cp16(g, sA + (size_t)(w * 8 + u) * 512);
    }
    // B tile (weights, [n][k])
    #pragma unroll
    for (int u = 0; u < 8; ++u) {
        int i = (w * 8 + u) * 64 + lane;
        int n = i >> 4, p = i & 15;
        const unsigned short* g = Wt + n * 128 + ((p ^ (n & 7)) << 3);
        async_cp16(g, sB + (size_t)(w * 8 + u) * 512);
    }
    __syncthreads();

    int m = lane & 15;
    int q = lane >> 4;
    int sw = m & 7;

    floatx4 acc[2][8] = {};
    int rA0 = w * 32 + m, rA1 = w * 32 + 16 + m;
    #pragma unroll
    for (int kk = 0; kk < 4; ++kk) {
        int cl = kk * 4 + q;            // logical 16B chunk within row
        int cp = cl ^ sw;               // physical chunk (row&7 == m&7 for all rows used)
        short8 a0 = *(const short8*)&sA[rA0 * 128 + (cp << 3)];
        short8 a1 = *(const short8*)&sA[rA1 * 128 + (cp << 3)];
        #pragma unroll
        for (int c = 0; c < 8; ++c) {
            int nr = c * 16 + m;
            short8 b = *(const short8*)&sB[nr * 128 + (cp << 3)];
            acc[0][c] = __builtin_amdgcn_mfma_f32_16x16x32_bf16(b, a0, acc[0][c], 0, 0, 0);
            acc[1][c] = __builtin_amdgcn_mfma_f32_16x16x32_bf16(b, a1, acc[1][c], 0, 0, 0);
        }
    }

    // D[ch = c*16 + q*4 + r][node = w*32 + h*16 + m]
    #pragma unroll
    for (int c = 0; c < 8; ++c) {
        int ch0 = c * 16 + q * 4;
        float4 bv = *(const float4*)(bias + ch0);
        #pragma unroll
        for (int h = 0; h < 2; ++h) {
            int node = r0 + w * 32 + h * 16 + m;
            if (node < N_NODES) {
                float v0 = acc[h][c][0] + bv.x;
                float v1 = acc[h][c][1] + bv.y;
                float v2 = acc[h][c][2] + bv.z;
                float v3 = acc[h][c][3] + bv.w;
                if (RELU_ST) {
                    v0 = fmaxf(v0, 0.f); v1 = fmaxf(v1, 0.f);
                    v2 = fmaxf(v2, 0.f); v3 = fmaxf(v3, 0.f);
                }
                ushort4 o;
                o.x = f2bf(v0); o.y = f2bf(v1); o.z = f2bf(v2); o.w = f2bf(v3);
                *(ushort4*)(Out + (size_t)node * 128 + ch0) = o;
            }
        }
    }
}

// ============================ BN stats pass ============================
#define ST_BLOCKS 250
#define ST_ROWS   400
__global__ __launch_bounds__(256)
void k_stats(const unsigned short* __restrict__ H,
             float* __restrict__ ssum, float* __restrict__ ssq) {
    __shared__ float rs[8][128];
    __shared__ float rq[8][128];
    int t  = threadIdx.x;
    int cq = t & 31;
    int r  = t >> 5;
    int row0 = blockIdx.x * ST_ROWS;
    float s0=0,s1=0,s2=0,s3=0,q0=0,q1=0,q2=0,q3=0;
    for (int i = r; i < ST_ROWS; i += 8) {
        ushort4 v = *(const ushort4*)(H + (size_t)(row0 + i) * 128 + cq * 4);
        float f0=bf2f(v.x), f1=bf2f(v.y), f2=bf2f(v.z), f3=bf2f(v.w);
        s0+=f0; s1+=f1; s2+=f2; s3+=f3;
        q0+=f0*f0; q1+=f1*f1; q2+=f2*f2; q3+=f3*f3;
    }
    rs[r][cq*4+0]=s0; rs[r][cq*4+1]=s1; rs[r][cq*4+2]=s2; rs[r][cq*4+3]=s3;
    rq[r][cq*4+0]=q0; rq[r][cq*4+1]=q1; rq[r][cq*4+2]=q2; rq[r][cq*4+3]=q3;
    __syncthreads();
    if (t < 128) {
        float a = 0.f, b = 0.f;
        #pragma unroll
        for (int j = 0; j < 8; ++j) { a += rs[j][t]; b += rq[j][t]; }
        atomicAdd(&ssum[t], a);
        atomicAdd(&ssq [t], b);
    }
}

__global__ void k_bnfin(const float* __restrict__ sum, const float* __restrict__ sq,
                        const float* __restrict__ gamma, const float* __restrict__ beta,
                        float* __restrict__ scale, float* __restrict__ shift) {
    int c = threadIdx.x;
    if (c < DIM) {
        float m   = sum[c] * (1.0f / N_NODES);
        float var = sq[c] * (1.0f / N_NODES) - m * m;
        float inv = rsqrtf(var + BN_EPS);
        float sc  = gamma[c] * inv;
        scale[c] = sc;
        shift[c] = beta[c] - m * sc;
    }
}

// ============================ BN apply (in-place, relu) ============================
__global__ __launch_bounds__(256)
void k_bn_apply(unsigned short* __restrict__ H, const float* __restrict__ scale,
                const float* __restrict__ shift) {
    __shared__ float ssc[128], ssh[128];
    int t = threadIdx.x;
    if (t < 128) { ssc[t] = scale[t]; ssh[t] = shift[t]; }
    __syncthreads();
    size_t idx = (size_t)blockIdx.x * 256 + t;     // ushort8 index, 1.6M total
    int k0 = ((int)idx & 15) * 8;
    short8 v = ((short8*)H)[idx];
    #pragma unroll
    for (int j = 0; j < 8; ++j) {
        float f = bf2f((unsigned short)v[j]);
        f = fmaxf(f * ssc[k0 + j] + ssh[k0 + j], 0.f);
        v[j] = (short)f2bf(f);
    }
    ((short8*)H)[idx] = v;
}

// ============================ Pooling ============================
#define POOL_BLOCKS 512
#define POOL_CHUNK  196
__global__ void k_pool(const unsigned short* __restrict__ h, const int* __restrict__ batch,
                       float* __restrict__ pooled) {
    int c  = threadIdx.x;
    int n0 = blockIdx.x * POOL_CHUNK;
    if (n0 >= N_NODES) return;
    int n1 = min(n0 + POOL_CHUNK, N_NODES);
    int g = batch[n0];
    float acc = 0.f;
    for (int i = n0; i < n1; ++i) {
        int gi = batch[i];
        if (gi != g) { atomicAdd(&pooled[g * DIM + c], acc); acc = 0.f; g = gi; }
        acc += bf2f(h[(size_t)i * DIM + c]);
    }
    atomicAdd(&pooled[g * DIM + c], acc);
}

// ============================ Readout ============================
__global__ void k_readout1(const float* __restrict__ pooled, const float* __restrict__ W,
                           const float* __restrict__ b, float* __restrict__ r1) {
    int idx = blockIdx.x * 256 + threadIdx.x;
    int g = idx >> 7, c = idx & 127;
    float s = b[c];
    const float* p = pooled + g * DIM;
    #pragma unroll 8
    for (int k = 0; k < DIM; ++k) s += p[k] * W[k * DIM + c];
    r1[idx] = fmaxf(s, 0.f);
}

__global__ void k_readout2(const float* __restrict__ r1, const float* __restrict__ W,
                           const float* __restrict__ b, float* __restrict__ out) {
    int idx = blockIdx.x * 256 + threadIdx.x;
    if (idx >= NUM_GRAPHS * OUT_CH) return;
    int g = idx / OUT_CH, c = idx % OUT_CH;
    float s = b[c];
    const float* r = r1 + g * DIM;
    #pragma unroll 8
    for (int k = 0; k < DIM; ++k) s += r[k] * W[k * OUT_CH + c];
    out[idx] = s;
}

// ============================ Launch ============================
extern "C" void kernel_launch(void* const* d_in, const int* in_sizes, int n_in,
                              void* d_out, int out_size, void* d_ws, size_t ws_size,
                              hipStream_t stream) {
    const float* x   = (const float*)d_in[0];
    const int*   ei  = (const int*)d_in[1];
    const int*   bat = (const int*)d_in[2];
    const float* W1a = (const float*)d_in[3];
    const float* b1a = (const float*)d_in[4];
    const float* ga  = (const float*)d_in[5];
    const float* ba  = (const float*)d_in[6];
    const float* W2a = (const float*)d_in[7];
    const float* b2a = (const float*)d_in[8];
    const float* W1b = (const float*)d_in[9];
    const float* b1b = (const float*)d_in[10];
    const float* gb  = (const float*)d_in[11];
    const float* bbt = (const float*)d_in[12];
    const float* W2b = (const float*)d_in[13];
    const float* b2b = (const float*)d_in[14];
    const float* Wl1 = (const float*)d_in[15];
    const float* bl1 = (const float*)d_in[16];
    const float* Wl2 = (const float*)d_in[17];
    const float* bl2 = (const float*)d_in[18];
    float* out = (float*)d_out;

    const int* src = ei;
    const int* dst = ei + N_EDGES;

    char* w = (char*)d_ws;
    size_t off = 0;
    auto alloc = [&](size_t bytes) -> char* {
        char* p = w + off; off += (bytes + 255) & ~(size_t)255; return p;
    };
    unsigned short* xb   = (unsigned short*)alloc((size_t)N_NODES * DIM * 2);
    unsigned short* nb0  = (unsigned short*)alloc((size_t)N_NODES * DIM * 2);
    unsigned short* nb1  = (unsigned short*)alloc((size_t)N_NODES * DIM * 2);
    unsigned short* Wtb  = (unsigned short*)alloc((size_t)4 * DIM * DIM * 2);
    uint2* pairs   = (uint2*)alloc((size_t)NB2 * CAP2 * 8);
    int*   row_ptr = (int*)  alloc((size_t)(N_NODES + 1) * 4);
    int*   col     = (int*)  alloc((size_t)N_EDGES * 4);
    int*   gcur    = (int*)  alloc((NB2 + 1) * 4);
    int*   bbase   = (int*)  alloc((NB2 + 1) * 4);
    float* ssumA   = (float*)alloc(DIM * 4);
    float* ssqA    = (float*)alloc(DIM * 4);
    float* ssumB   = (float*)alloc(DIM * 4);
    float* ssqB    = (float*)alloc(DIM * 4);
    float* scale   = (float*)alloc(DIM * 4);
    float* shift   = (float*)alloc(DIM * 4);
    float* pooled  = (float*)alloc((size_t)NUM_GRAPHS * DIM * 4);
    float* r1      = (float*)alloc((size_t)NUM_GRAPHS * DIM * 4);

    hipMemsetAsync(gcur,  0, (NB2 + 1) * 4, stream);
    hipMemsetAsync(ssumA, 0, DIM * 4 * 4, stream);   // ssumA/ssqA/ssumB/ssqB contiguous
    hipMemsetAsync(pooled,0, (size_t)NUM_GRAPHS * DIM * 4, stream);

    // CSR build
    k_bucket<<<(N_EDGES + 4095) / 4096, 256, 0, stream>>>(src, dst, gcur, pairs);
    k_bscan<<<1, 512, 0, stream>>>(gcur, bbase, row_ptr);
    k_csr<<<NB2, 256, 0, stream>>>(pairs, gcur, bbase, row_ptr, col);

    // dtype prep
    k_cvt_x<<<(N_NODES * DIM / 4) / 256, 256, 0, stream>>>(x, xb);
    k_prep_w<<<dim3(64, 4), 256, 0, stream>>>(W1a, W2a, W1b, W2b, Wtb);
    const unsigned short* Wt1a = Wtb;
    const unsigned short* Wt2a = Wtb + DIM * DIM;
    const unsigned short* Wt1b = Wtb + 2 * DIM * DIM;
    const unsigned short* Wt2b = Wtb + 3 * DIM * DIM;

    int agg_blocks  = (N_NODES * 64) / 256;
    int gemm_blocks = (N_NODES + 127) / 128;
    int bn_blocks   = (N_NODES * DIM / 8) / 256;     // 6250

    // conv1
    k_agg<<<agg_blocks, 256, 0, stream>>>(xb, nb0, row_ptr, col);
    k_gemm<false><<<gemm_blocks, 256, 0, stream>>>(nb0, nb1, Wt1a, b1a);
    k_stats<<<ST_BLOCKS, 256, 0, stream>>>(nb1, ssumA, ssqA);
    k_bnfin<<<1, 128, 0, stream>>>(ssumA, ssqA, ga, ba, scale, shift);
    k_bn_apply<<<bn_blocks, 256, 0, stream>>>(nb1, scale, shift);
    k_gemm<true><<<gemm_blocks, 256, 0, stream>>>(nb1, nb0, Wt2a, b2a);
    // conv2
    k_agg<<<agg_blocks, 256, 0, stream>>>(nb0, nb1, row_ptr, col);
    k_gemm<false><<<gemm_blocks, 256, 0, stream>>>(nb1, nb0, Wt1b, b1b);
    k_stats<<<ST_BLOCKS, 256, 0, stream>>>(nb0, ssumB, ssqB);
    k_bnfin<<<1, 128, 0, stream>>>(ssumB, ssqB, gb, bbt, scale, shift);
    k_bn_apply<<<bn_blocks, 256, 0, stream>>>(nb0, scale, shift);
    k_gemm<true><<<gemm_blocks, 256, 0, stream>>>(nb0, nb1, Wt2b, b2b);
    // readout
    k_pool<<<POOL_BLOCKS, 128, 0, stream>>>(nb1, bat, pooled);
    k_readout1<<<(NUM_GRAPHS * DIM) / 256, 256, 0, stream>>>(pooled, Wl1, bl1, r1);
    k_readout2<<<(NUM_GRAPHS * OUT_CH + 255) / 256, 256, 0, stream>>>(r1, Wl2, bl2, out);
}

// Round 6
// 512.982 us; speedup vs baseline: 1.8168x; 1.0259x over previous
//
#include <hip/hip_runtime.h>

#define N_NODES    100000
#define N_EDGES    1600000
#define DIM        128
#define OUT_CH     10
#define NUM_GRAPHS 128
#define BN_EPS     1e-5f

// bucket partition params (256 nodes/bucket)
#define BSHIFT   8
#define NB2      391         // ceil(100000 / 256)
#define CAP2     5120        // expected ~4092/bucket, +16 sigma

typedef __attribute__((ext_vector_type(8))) short short8;
typedef __attribute__((ext_vector_type(4))) float floatx4;

__device__ inline float bf2f(unsigned short u) {
    union { unsigned i; float f; } v; v.i = (unsigned)u << 16; return v.f;
}
__device__ inline unsigned short f2bf(float f) {
    union { float f; unsigned i; } v; v.f = f;
    unsigned r = (v.i + 0x7fffu + ((v.i >> 16) & 1u)) >> 16;
    return (unsigned short)r;
}

__device__ inline void async_cp16(const unsigned short* g, unsigned short* l) {
    __builtin_amdgcn_global_load_lds(
        (const __attribute__((address_space(1))) void*)g,
        (__attribute__((address_space(3))) void*)l, 16, 0, 0);
}

// ===================== bucket partition (src,dst) by dst>>8 =====================
__global__ __launch_bounds__(256)
void k_bucket(const int* __restrict__ src, const int* __restrict__ dst,
              int* __restrict__ gcur, uint2* __restrict__ pairs) {
    __shared__ int h[NB2];
    int t = threadIdx.x;
    for (int i = t; i < NB2; i += 256) h[i] = 0;
    __syncthreads();
    int base = blockIdx.x * 4096;
    #pragma unroll
    for (int i = 0; i < 16; ++i) {
        int idx = base + i * 256 + t;
        if (idx < N_EDGES) atomicAdd(&h[dst[idx] >> BSHIFT], 1);
    }
    __syncthreads();
    for (int i = t; i < NB2; i += 256) h[i] = atomicAdd(&gcur[i], h[i]);
    __syncthreads();
    #pragma unroll
    for (int i = 0; i < 16; ++i) {
        int idx = base + i * 256 + t;
        if (idx < N_EDGES) {
            int d = dst[idx];
            int b = d >> BSHIFT;
            int pos = atomicAdd(&h[b], 1);
            if (pos < CAP2) pairs[(size_t)b * CAP2 + pos] = make_uint2((unsigned)src[idx], (unsigned)d);
        }
    }
}

// exclusive scan of bucket sizes
__global__ void k_bscan(const int* __restrict__ gcur, int* __restrict__ bbase,
                        int* __restrict__ row_ptr) {
    __shared__ int sh[512];
    int t = threadIdx.x;
    int v = (t < NB2) ? min(gcur[t], CAP2) : 0;
    sh[t] = v; __syncthreads();
    for (int off = 1; off < 512; off <<= 1) {
        int tmp = (t >= off) ? sh[t - off] : 0;
        __syncthreads();
        sh[t] += tmp;
        __syncthreads();
    }
    if (t < NB2) bbase[t] = sh[t] - v;
    if (t == NB2 - 1) { bbase[NB2] = sh[t]; row_ptr[N_NODES] = sh[t]; }
}

// per-bucket: hist -> scan -> row_ptr + direct col placement
__global__ __launch_bounds__(256)
void k_csr(const uint2* __restrict__ pairs, const int* __restrict__ gcur,
           const int* __restrict__ bbase, int* __restrict__ row_ptr,
           int* __restrict__ col) {
    __shared__ int hist[256];
    __shared__ int cur[256];
    int bi = blockIdx.x, t = threadIdx.x;
    hist[t] = 0; __syncthreads();
    int n = min(gcur[bi], CAP2);
    const uint2* P = pairs + (size_t)bi * CAP2;
    for (int i = t; i < n; i += 256)
        atomicAdd(&hist[P[i].y & 255], 1);
    __syncthreads();
    int self = hist[t];
    cur[t] = self; __syncthreads();
    for (int off = 1; off < 256; off <<= 1) {
        int tmp = (t >= off) ? cur[t - off] : 0;
        __syncthreads();
        cur[t] += tmp;
        __syncthreads();
    }
    int excl = cur[t] - self;
    int base = bbase[bi];
    int node = (bi << 8) + t;
    if (node < N_NODES) row_ptr[node] = base + excl;
    __syncthreads();
    cur[t] = base + excl;
    __syncthreads();
    for (int i = t; i < n; i += 256) {
        uint2 e = P[i];
        int pos = atomicAdd(&cur[e.y & 255], 1);
        col[pos] = (int)e.x;
    }
}

// ============================ dtype prep ============================
__global__ void k_cvt_x(const float* __restrict__ x, unsigned short* __restrict__ xb) {
    int idx = blockIdx.x * 256 + threadIdx.x;
    float4 v = ((const float4*)x)[idx];
    ushort4 o;
    o.x = f2bf(v.x); o.y = f2bf(v.y); o.z = f2bf(v.z); o.w = f2bf(v.w);
    ((ushort4*)xb)[idx] = o;
}

__global__ void k_prep_w(const float* __restrict__ W0, const float* __restrict__ W1,
                         const float* __restrict__ W2, const float* __restrict__ W3,
                         unsigned short* __restrict__ Wt) {
    const float* Ws[4] = {W0, W1, W2, W3};
    const float* W = Ws[blockIdx.y];
    unsigned short* o = Wt + blockIdx.y * (DIM * DIM);
    int idx = blockIdx.x * 256 + threadIdx.x;
    int n = idx >> 7, k = idx & 127;
    o[idx] = f2bf(W[k * DIM + n]);
}

// ============================ Aggregation (bf16, 4 gathers in flight/half) ============================
__global__ void k_agg(const unsigned short* __restrict__ X,
                      unsigned short* __restrict__ Out,
                      const int* __restrict__ row_ptr, const int* __restrict__ col) {
    int wid = (blockIdx.x * 256 + threadIdx.x) >> 6;
    if (wid >= N_NODES) return;
    int lane = threadIdx.x & 63;
    int half = lane >> 5, m = lane & 31;
    const ushort4* X4 = (const ushort4*)X;

    float a0=0.f,a1=0.f,a2=0.f,a3=0.f;
    float c0=0.f,c1=0.f,c2=0.f,c3=0.f;
    if (half == 0) {
        ushort4 sv = X4[(size_t)wid * 32 + m];
        a0 = bf2f(sv.x); a1 = bf2f(sv.y); a2 = bf2f(sv.z); a3 = bf2f(sv.w);
    }
    int s = row_ptr[wid], e = row_ptr[wid + 1];
    int p = s + half;
    for (; p + 6 < e; p += 8) {
        int n0 = col[p], n1 = col[p + 2], n2 = col[p + 4], n3 = col[p + 6];
        ushort4 v0 = X4[(size_t)n0 * 32 + m];
        ushort4 v1 = X4[(size_t)n1 * 32 + m];
        ushort4 v2 = X4[(size_t)n2 * 32 + m];
        ushort4 v3 = X4[(size_t)n3 * 32 + m];
        a0 += bf2f(v0.x); a1 += bf2f(v0.y); a2 += bf2f(v0.z); a3 += bf2f(v0.w);
        c0 += bf2f(v1.x); c1 += bf2f(v1.y); c2 += bf2f(v1.z); c3 += bf2f(v1.w);
        a0 += bf2f(v2.x); a1 += bf2f(v2.y); a2 += bf2f(v2.z); a3 += bf2f(v2.w);
        c0 += bf2f(v3.x); c1 += bf2f(v3.y); c2 += bf2f(v3.z); c3 += bf2f(v3.w);
    }
    for (; p < e; p += 2) {
        ushort4 v = X4[(size_t)col[p] * 32 + m];
        a0 += bf2f(v.x); a1 += bf2f(v.y); a2 += bf2f(v.z); a3 += bf2f(v.w);
    }
    a0 += c0; a1 += c1; a2 += c2; a3 += c3;
    a0 += __shfl_xor(a0, 32);
    a1 += __shfl_xor(a1, 32);
    a2 += __shfl_xor(a2, 32);
    a3 += __shfl_xor(a3, 32);
    if (half == 0) {
        ushort4 o;
        o.x = f2bf(a0); o.y = f2bf(a1); o.z = f2bf(a2); o.w = f2bf(a3);
        ((ushort4*)Out)[(size_t)wid * 32 + m] = o;
    }
}

// ============================ MFMA GEMM [N,128] @ [128,128] ============================
// 128 rows/block, 4 waves. A-frags load straight from global (coalesced 16
// rows x 64B per instr, L2/L3-hot, zero cross-wave reuse => no LDS for A).
// B (weights) async-DMA'd to LDS with XOR chunk swizzle (4-wave reuse).
// BN_LOAD: in-register y = relu(a*scale[k]+shift[k]) on the A-frags.
template<bool BN_LOAD, bool RELU_ST>
__global__ __launch_bounds__(256)
void k_gemm(const unsigned short* __restrict__ In, unsigned short* __restrict__ Out,
            const unsigned short* __restrict__ Wt, const float* __restrict__ bias,
            const float* __restrict__ scale, const float* __restrict__ shift) {
    __shared__ __align__(16) unsigned short sB[128 * 128];   // 32 KB
    __shared__ float ssc[128], ssh[128];

    int t = threadIdx.x;
    int w = t >> 6, lane = t & 63;
    int r0 = blockIdx.x * 128;
    int m = lane & 15;
    int q = lane >> 4;

    // A-frag global loads (issued first; overlap the B DMA)
    int rowA0 = min(r0 + w * 32 + m,      N_NODES - 1);
    int rowA1 = min(r0 + w * 32 + 16 + m, N_NODES - 1);
    short8 a0[4], a1[4];
    #pragma unroll
    for (int kk = 0; kk < 4; ++kk) {
        a0[kk] = *(const short8*)(In + (size_t)rowA0 * 128 + kk * 32 + q * 8);
        a1[kk] = *(const short8*)(In + (size_t)rowA1 * 128 + kk * 32 + q * 8);
    }

    // B tile -> LDS, chunk (n,p) slot holds source chunk p ^ (n&7)
    #pragma unroll
    for (int u = 0; u < 8; ++u) {
        int i = (w * 8 + u) * 64 + lane;
        int n = i >> 4, p = i & 15;
        async_cp16(Wt + n * 128 + ((p ^ (n & 7)) << 3), sB + (size_t)(w * 8 + u) * 512);
    }
    if (BN_LOAD && t < 128) { ssc[t] = scale[t]; ssh[t] = shift[t]; }
    __syncthreads();

    if (BN_LOAD) {
        #pragma unroll
        for (int kk = 0; kk < 4; ++kk) {
            int base = kk * 32 + q * 8;
            float4 c0 = *(const float4*)&ssc[base];
            float4 c1 = *(const float4*)&ssc[base + 4];
            float4 h0 = *(const float4*)&ssh[base];
            float4 h1 = *(const float4*)&ssh[base + 4];
            float sc[8] = {c0.x,c0.y,c0.z,c0.w,c1.x,c1.y,c1.z,c1.w};
            float sh[8] = {h0.x,h0.y,h0.z,h0.w,h1.x,h1.y,h1.z,h1.w};
            #pragma unroll
            for (int j = 0; j < 8; ++j) {
                float f0 = fmaxf(bf2f((unsigned short)a0[kk][j]) * sc[j] + sh[j], 0.f);
                float f1 = fmaxf(bf2f((unsigned short)a1[kk][j]) * sc[j] + sh[j], 0.f);
                a0[kk][j] = (short)f2bf(f0);
                a1[kk][j] = (short)f2bf(f1);
            }
        }
    }

    int sw = m & 7;
    floatx4 acc[2][8] = {};
    #pragma unroll
    for (int kk = 0; kk < 4; ++kk) {
        int cp = (kk * 4 + q) ^ sw;
        #pragma unroll
        for (int c = 0; c < 8; ++c) {
            int nr = c * 16 + m;
            short8 b = *(const short8*)&sB[nr * 128 + (cp << 3)];
            acc[0][c] = __builtin_amdgcn_mfma_f32_16x16x32_bf16(b, a0[kk], acc[0][c], 0, 0, 0);
            acc[1][c] = __builtin_amdgcn_mfma_f32_16x16x32_bf16(b, a1[kk], acc[1][c], 0, 0, 0);
        }
    }

    // D[ch = c*16 + q*4 + r][node = w*32 + h*16 + m]
    #pragma unroll
    for (int c = 0; c < 8; ++c) {
        int ch0 = c * 16 + q * 4;
        float4 bv = *(const float4*)(bias + ch0);
        #pragma unroll
        for (int h = 0; h < 2; ++h) {
            int node = r0 + w * 32 + h * 16 + m;
            if (node < N_NODES) {
                float v0 = acc[h][c][0] + bv.x;
                float v1 = acc[h][c][1] + bv.y;
                float v2 = acc[h][c][2] + bv.z;
                float v3 = acc[h][c][3] + bv.w;
                if (RELU_ST) {
                    v0 = fmaxf(v0, 0.f); v1 = fmaxf(v1, 0.f);
                    v2 = fmaxf(v2, 0.f); v3 = fmaxf(v3, 0.f);
                }
                ushort4 o;
                o.x = f2bf(v0); o.y = f2bf(v1); o.z = f2bf(v2); o.w = f2bf(v3);
                *(ushort4*)(Out + (size_t)node * 128 + ch0) = o;
            }
        }
    }
}

// ============================ BN stats pass ============================
#define ST_BLOCKS 250
#define ST_ROWS   400
__global__ __launch_bounds__(256)
void k_stats(const unsigned short* __restrict__ H,
             float* __restrict__ ssum, float* __restrict__ ssq) {
    __shared__ float rs[8][128];
    __shared__ float rq[8][128];
    int t  = threadIdx.x;
    int cq = t & 31;
    int r  = t >> 5;
    int row0 = blockIdx.x * ST_ROWS;
    float s0=0,s1=0,s2=0,s3=0,q0=0,q1=0,q2=0,q3=0;
    for (int i = r; i < ST_ROWS; i += 8) {
        ushort4 v = *(const ushort4*)(H + (size_t)(row0 + i) * 128 + cq * 4);
        float f0=bf2f(v.x), f1=bf2f(v.y), f2=bf2f(v.z), f3=bf2f(v.w);
        s0+=f0; s1+=f1; s2+=f2; s3+=f3;
        q0+=f0*f0; q1+=f1*f1; q2+=f2*f2; q3+=f3*f3;
    }
    rs[r][cq*4+0]=s0; rs[r][cq*4+1]=s1; rs[r][cq*4+2]=s2; rs[r][cq*4+3]=s3;
    rq[r][cq*4+0]=q0; rq[r][cq*4+1]=q1; rq[r][cq*4+2]=q2; rq[r][cq*4+3]=q3;
    __syncthreads();
    if (t < 128) {
        float a = 0.f, b = 0.f;
        #pragma unroll
        for (int j = 0; j < 8; ++j) { a += rs[j][t]; b += rq[j][t]; }
        atomicAdd(&ssum[t], a);
        atomicAdd(&ssq [t], b);
    }
}

__global__ void k_bnfin(const float* __restrict__ sum, const float* __restrict__ sq,
                        const float* __restrict__ gamma, const float* __restrict__ beta,
                        float* __restrict__ scale, float* __restrict__ shift) {
    int c = threadIdx.x;
    if (c < DIM) {
        float m   = sum[c] * (1.0f / N_NODES);
        float var = sq[c] * (1.0f / N_NODES) - m * m;
        float inv = rsqrtf(var + BN_EPS);
        float sc  = gamma[c] * inv;
        scale[c] = sc;
        shift[c] = beta[c] - m * sc;
    }
}

// ============================ Pooling ============================
#define POOL_BLOCKS 512
#define POOL_CHUNK  196
__global__ void k_pool(const unsigned short* __restrict__ h, const int* __restrict__ batch,
                       float* __restrict__ pooled) {
    int c  = threadIdx.x;
    int n0 = blockIdx.x * POOL_CHUNK;
    if (n0 >= N_NODES) return;
    int n1 = min(n0 + POOL_CHUNK, N_NODES);
    int g = batch[n0];
    float acc = 0.f;
    for (int i = n0; i < n1; ++i) {
        int gi = batch[i];
        if (gi != g) { atomicAdd(&pooled[g * DIM + c], acc); acc = 0.f; g = gi; }
        acc += bf2f(h[(size_t)i * DIM + c]);
    }
    atomicAdd(&pooled[g * DIM + c], acc);
}

// ============================ Readout ============================
__global__ void k_readout1(const float* __restrict__ pooled, const float* __restrict__ W,
                           const float* __restrict__ b, float* __restrict__ r1) {
    int idx = blockIdx.x * 256 + threadIdx.x;
    int g = idx >> 7, c = idx & 127;
    float s = b[c];
    const float* p = pooled + g * DIM;
    #pragma unroll 8
    for (int k = 0; k < DIM; ++k) s += p[k] * W[k * DIM + c];
    r1[idx] = fmaxf(s, 0.f);
}

__global__ void k_readout2(const float* __restrict__ r1, const float* __restrict__ W,
                           const float* __restrict__ b, float* __restrict__ out) {
    int idx = blockIdx.x * 256 + threadIdx.x;
    if (idx >= NUM_GRAPHS * OUT_CH) return;
    int g = idx / OUT_CH, c = idx % OUT_CH;
    float s = b[c];
    const float* r = r1 + g * DIM;
    #pragma unroll 8
    for (int k = 0; k < DIM; ++k) s += r[k] * W[k * OUT_CH + c];
    out[idx] = s;
}

// ============================ Launch ============================
extern "C" void kernel_launch(void* const* d_in, const int* in_sizes, int n_in,
                              void* d_out, int out_size, void* d_ws, size_t ws_size,
                              hipStream_t stream) {
    const float* x   = (const float*)d_in[0];
    const int*   ei  = (const int*)d_in[1];
    const int*   bat = (const int*)d_in[2];
    const float* W1a = (const float*)d_in[3];
    const float* b1a = (const float*)d_in[4];
    const float* ga  = (const float*)d_in[5];
    const float* ba  = (const float*)d_in[6];
    const float* W2a = (const float*)d_in[7];
    const float* b2a = (const float*)d_in[8];
    const float* W1b = (const float*)d_in[9];
    const float* b1b = (const float*)d_in[10];
    const float* gb  = (const float*)d_in[11];
    const float* bbt = (const float*)d_in[12];
    const float* W2b = (const float*)d_in[13];
    const float* b2b = (const float*)d_in[14];
    const float* Wl1 = (const float*)d_in[15];
    const float* bl1 = (const float*)d_in[16];
    const float* Wl2 = (const float*)d_in[17];
    const float* bl2 = (const float*)d_in[18];
    float* out = (float*)d_out;

    const int* src = ei;
    const int* dst = ei + N_EDGES;

    char* w = (char*)d_ws;
    size_t off = 0;
    auto alloc = [&](size_t bytes) -> char* {
        char* p = w + off; off += (bytes + 255) & ~(size_t)255; return p;
    };
    unsigned short* xb   = (unsigned short*)alloc((size_t)N_NODES * DIM * 2);
    unsigned short* nb0  = (unsigned short*)alloc((size_t)N_NODES * DIM * 2);
    unsigned short* nb1  = (unsigned short*)alloc((size_t)N_NODES * DIM * 2);
    unsigned short* Wtb  = (unsigned short*)alloc((size_t)4 * DIM * DIM * 2);
    uint2* pairs   = (uint2*)alloc((size_t)NB2 * CAP2 * 8);
    int*   row_ptr = (int*)  alloc((size_t)(N_NODES + 1) * 4);
    int*   col     = (int*)  alloc((size_t)N_EDGES * 4);
    int*   gcur    = (int*)  alloc((NB2 + 1) * 4);
    int*   bbase   = (int*)  alloc((NB2 + 1) * 4);
    float* ssumA   = (float*)alloc(DIM * 4);
    float* ssqA    = (float*)alloc(DIM * 4);
    float* ssumB   = (float*)alloc(DIM * 4);
    float* ssqB    = (float*)alloc(DIM * 4);
    float* scale   = (float*)alloc(DIM * 4);
    float* shift   = (float*)alloc(DIM * 4);
    float* pooled  = (float*)alloc((size_t)NUM_GRAPHS * DIM * 4);
    float* r1      = (float*)alloc((size_t)NUM_GRAPHS * DIM * 4);

    hipMemsetAsync(gcur,  0, (NB2 + 1) * 4, stream);
    hipMemsetAsync(ssumA, 0, DIM * 4 * 4, stream);   // ssumA/ssqA/ssumB/ssqB contiguous
    hipMemsetAsync(pooled,0, (size_t)NUM_GRAPHS * DIM * 4, stream);

    // CSR build
    k_bucket<<<(N_EDGES + 4095) / 4096, 256, 0, stream>>>(src, dst, gcur, pairs);
    k_bscan<<<1, 512, 0, stream>>>(gcur, bbase, row_ptr);
    k_csr<<<NB2, 256, 0, stream>>>(pairs, gcur, bbase, row_ptr, col);

    // dtype prep
    k_cvt_x<<<(N_NODES * DIM / 4) / 256, 256, 0, stream>>>(x, xb);
    k_prep_w<<<dim3(64, 4), 256, 0, stream>>>(W1a, W2a, W1b, W2b, Wtb);
    const unsigned short* Wt1a = Wtb;
    const unsigned short* Wt2a = Wtb + DIM * DIM;
    const unsigned short* Wt1b = Wtb + 2 * DIM * DIM;
    const unsigned short* Wt2b = Wtb + 3 * DIM * DIM;

    int agg_blocks  = (N_NODES * 64) / 256;
    int gemm_blocks = (N_NODES + 127) / 128;

    // conv1
    k_agg<<<agg_blocks, 256, 0, stream>>>(xb, nb0, row_ptr, col);
    k_gemm<false, false><<<gemm_blocks, 256, 0, stream>>>(nb0, nb1, Wt1a, b1a, nullptr, nullptr);
    k_stats<<<ST_BLOCKS, 256, 0, stream>>>(nb1, ssumA, ssqA);
    k_bnfin<<<1, 128, 0, stream>>>(ssumA, ssqA, ga, ba, scale, shift);
    k_gemm<true, true><<<gemm_blocks, 256, 0, stream>>>(nb1, nb0, Wt2a, b2a, scale, shift);
    // conv2
    k_agg<<<agg_blocks, 256, 0, stream>>>(nb0, nb1, row_ptr, col);
    k_gemm<false, false><<<gemm_blocks, 256, 0, stream>>>(nb1, nb0, Wt1b, b1b, nullptr, nullptr);
    k_stats<<<ST_BLOCKS, 256, 0, stream>>>(nb0, ssumB, ssqB);
    k_bnfin<<<1, 128, 0, stream>>>(ssumB, ssqB, gb, bbt, scale, shift);
    k_gemm<true, true><<<gemm_blocks, 256, 0, stream>>>(nb0, nb1, Wt2b, b2b, scale, shift);
    // readout
    k_pool<<<POOL_BLOCKS, 128, 0, stream>>>(nb1, bat, pooled);
    k_readout1<<<(NUM_GRAPHS * DIM) / 256, 256, 0, stream>>>(pooled, Wl1, bl1, r1);
    k_readout2<<<(NUM_GRAPHS * OUT_CH + 255) / 256, 256, 0, stream>>>(r1, Wl2, bl2, out);
}